// Round 1
// baseline (462.122 us; speedup 1.0000x reference)
//
#include <hip/hip_runtime.h>

// out[b,t,u] = h0[b,u] + 0.5f * cumsum_t(x[b,:,u])
// x: (16, 4096, 1024) fp32, h0: (16, 1024) fp32, out: (16, 4096, 1024) fp32.
//
// One thread owns one (b,u) chain, iterating t sequentially (the scan
// dependency), with a 32-deep double-buffered load pipeline to keep ~2 MiB
// of HBM reads in flight chip-wide. Grid = 256 blocks x 64 threads -> one
// wave per CU across all 256 CUs.

#define T_DIM 4096
#define U_DIM 1024
#define B_DIM 16
#define UNROLL 32

__global__ __launch_bounds__(64) void rac_scan_kernel(
    const float* __restrict__ x,
    const float* __restrict__ h0,
    float* __restrict__ out) {
  const int blk = blockIdx.x;            // 0..255
  const int b = blk >> 4;                // 16 u-tiles per b
  const int utile = blk & 15;
  const int u = utile * 64 + threadIdx.x;

  const size_t base = (size_t)b * T_DIM * U_DIM + (size_t)u;
  const float* xp = x + base;
  float* op = out + base;

  float acc = h0[b * U_DIM + u];

  float va[UNROLL];
  float vb[UNROLL];

#define LOAD_CHUNK(buf, t0)                                                  \
  _Pragma("unroll") for (int i = 0; i < UNROLL; ++i) {                       \
    (buf)[i] = __builtin_nontemporal_load(xp + (size_t)((t0) + i) * U_DIM);  \
  }

#define CONSUME_CHUNK(buf, t0)                                               \
  _Pragma("unroll") for (int i = 0; i < UNROLL; ++i) {                       \
    acc = fmaf(0.5f, (buf)[i], acc);                                         \
    __builtin_nontemporal_store(acc, op + (size_t)((t0) + i) * U_DIM);       \
  }

  // Prologue: fill buffer A for chunk 0.
  LOAD_CHUNK(va, 0)

  // Steady state: ping-pong A/B so one chunk's loads are in flight while the
  // other chunk's fma+store chain retires.
  for (int t0 = 0; t0 < T_DIM; t0 += 2 * UNROLL) {
    LOAD_CHUNK(vb, t0 + UNROLL)
    CONSUME_CHUNK(va, t0)
    if (t0 + 2 * UNROLL < T_DIM) {
      LOAD_CHUNK(va, t0 + 2 * UNROLL)
    }
    CONSUME_CHUNK(vb, t0 + UNROLL)
  }

#undef LOAD_CHUNK
#undef CONSUME_CHUNK
}

extern "C" void kernel_launch(void* const* d_in, const int* in_sizes, int n_in,
                              void* d_out, int out_size, void* d_ws, size_t ws_size,
                              hipStream_t stream) {
  const float* x = (const float*)d_in[0];
  const float* h0 = (const float*)d_in[1];
  float* out = (float*)d_out;

  dim3 grid(B_DIM * (U_DIM / 64));  // 256 blocks
  dim3 block(64);                   // 1 wave each
  rac_scan_kernel<<<grid, block, 0, stream>>>(x, h0, out);
}